// Round 11
// baseline (316.432 us; speedup 1.0000x reference)
//
#include <hip/hip_runtime.h>
#include <cstdint>
#include <cstddef>

// GraphSAGE 3-layer, N=100000 nodes, E=1600000 edges, dims 64->64->64->32.
// Transform-then-aggregate; padded CSR via 256-node super-buckets (2 kernels);
// MFMA bf16 dual GEMMs (t=h@Wl, r=h@Wr+b fp32); t for layers 0/1 stored as
// fp8 e4m3 (64B row = 1 line) to halve the gather's cross-XCD fetch floor;
// t2 (final layer) stays bf16, r always fp32.
// R4: LDS-atomic aggregation is 12x slower than CSR gather — don't revisit.
// R6: short scatter runs -> 64B-line write amplification.
// R7: 196-block bin_coarse latency-bound; LDS-cache + 782 blocks.
// R8: GEMMs on mfma_f32_16x16x32_bf16 (fp32 VALU was the bound).
// R10 post-mortem: gather+GEMM fusion halves occupancy (27KB LDS) and
// couples gather imbalance to the GEMM via the barrier — keep them separate.

constexpr int SBW = 256;     // dst nodes per super-bucket
constexpr int LOGSBW = 8;
constexpr int CAPS = 4608;   // super capacity; mean 4096, sigma ~64 (+8σ)
constexpr int CHK = 2048;    // edges per bin_coarse block -> 782 blocks

typedef __attribute__((ext_vector_type(8))) short s16x8;
typedef __attribute__((ext_vector_type(4))) float f32x4;
typedef __attribute__((ext_vector_type(2))) float f32x2;

__device__ inline unsigned short f2bf(float f) {
  unsigned u = __builtin_bit_cast(unsigned, f);
  u += 0x7FFFu + ((u >> 16) & 1u);          // round-to-nearest-even
  return (unsigned short)(u >> 16);
}
__device__ inline float bf2f(unsigned short b) {
  unsigned u = ((unsigned)b) << 16;
  return __builtin_bit_cast(float, u);
}
__device__ inline unsigned char f2fp8(float f) {
  int p = __builtin_amdgcn_cvt_pk_fp8_f32(f, f, 0, false);
  return (unsigned char)(p & 0xFF);
}

// ---------------- pass 1: coarse bin into 256-node super-buckets ----------

__global__ __launch_bounds__(256) void bin_coarse(const int* __restrict__ src,
                                                  const int* __restrict__ dst,
                                                  int* __restrict__ bcur,
                                                  unsigned int* __restrict__ coarse,
                                                  int NSB, int E) {
  __shared__ int h[512];
  __shared__ unsigned ed[CHK];
  __shared__ short sb[CHK];
  const int tid = threadIdx.x;
  for (int i = tid; i < NSB; i += 256) h[i] = 0;
  __syncthreads();
  const int e0 = blockIdx.x * CHK;
  const int e1 = min(E, e0 + CHK);
  for (int e = e0 + tid; e < e1; e += 256) {
    int d = dst[e];
    int s = src[e];
    int b = d >> LOGSBW;
    ed[e - e0] = (unsigned)s | ((unsigned)(d & (SBW - 1)) << 17);
    sb[e - e0] = (short)b;
    atomicAdd(&h[b], 1);
  }
  __syncthreads();
  for (int i = tid; i < NSB; i += 256) {
    int c = h[i];
    h[i] = c ? (i * CAPS + atomicAdd(&bcur[i], c)) : 0;  // slot -> abs cursor
  }
  __syncthreads();
  const int n = e1 - e0;
  for (int k = tid; k < n; k += 256) {
    int b = sb[k];
    int pos = atomicAdd(&h[b], 1);
    if (pos < (b + 1) * CAPS)                 // overflow guard (never taken)
      coarse[pos] = ed[k];
  }
}

// ---------------- pass 2: per-super count/scan/sort -> padded CSR ---------

__global__ __launch_bounds__(256) void super_csr(const unsigned int* __restrict__ coarse,
                                                 const int* __restrict__ bcur,
                                                 int* __restrict__ rowstart,
                                                 int* __restrict__ degarr,
                                                 float* __restrict__ deg_inv,
                                                 int* __restrict__ colidx,
                                                 int N) {
  __shared__ int cnt[SBW];
  __shared__ int sc[SBW];
  __shared__ int cur[SBW];
  const int b = blockIdx.x;
  const int tid = threadIdx.x;
  cnt[tid] = 0;
  __syncthreads();
  const int ec = min(bcur[b], CAPS);
  const int base = b * CAPS;
  for (int e = tid; e < ec; e += 256)
    atomicAdd(&cnt[coarse[base + e] >> 17], 1);
  __syncthreads();
  int v = cnt[tid];
  sc[tid] = v;
  __syncthreads();
  for (int off = 1; off < SBW; off <<= 1) {
    int y = sc[tid];
    if (tid >= off) y += sc[tid - off];
    __syncthreads();
    sc[tid] = y;
    __syncthreads();
  }
  int ex = sc[tid] - v;                       // exclusive prefix
  cur[tid] = ex;
  int gn = b * SBW + tid;
  if (gn < N) {
    rowstart[gn] = base + ex;
    degarr[gn] = v;
    deg_inv[gn] = 1.0f / (float)(v > 1 ? v : 1);
  }
  __syncthreads();
  for (int e = tid; e < ec; e += 256) {
    unsigned p = coarse[base + e];
    int dl = (int)(p >> 17);
    int s = (int)(p & 0x1FFFFu);
    int l = atomicAdd(&cur[dl], 1);
    colidx[base + l] = s;
  }
}

// ---------------- shared LDS weight staging (b32 writes, conflict-light) --
// Wt layout: col-major rows of K with SK-short stride; Wt[c*SK+k]=Wl[k][c],
// Wt[(c+DOUT)*SK+k]=Wr[k][c].

template <int DOUT, int SK>
__device__ inline void stage_weights(short* Wt, const float* __restrict__ Wl,
                                     const float* __restrict__ Wr, int tid) {
  for (int idx = tid; idx < DOUT * 32; idx += 256) {
    int c = idx >> 5;
    int k2 = (idx & 31) << 1;
    unsigned l0 = f2bf(Wl[k2 * DOUT + c]);
    unsigned l1 = f2bf(Wl[(k2 + 1) * DOUT + c]);
    *(unsigned*)&Wt[c * SK + k2] = l0 | (l1 << 16);
    unsigned r0 = f2bf(Wr[k2 * DOUT + c]);
    unsigned r1 = f2bf(Wr[(k2 + 1) * DOUT + c]);
    *(unsigned*)&Wt[(c + DOUT) * SK + k2] = r0 | (r1 << 16);
  }
}

// ---------------- layer-0 MFMA dual GEMM, fp32 input ----------------------
// C/D layout: col=lane&15, row=(lane>>4)*4+reg (m89-verified). t out fp8.

__global__ __launch_bounds__(256) void gemm0_mfma(const float* __restrict__ x,
                                                  const float* __restrict__ Wl,
                                                  const float* __restrict__ Wr,
                                                  const float* __restrict__ bias,
                                                  unsigned char* __restrict__ t_out,
                                                  float* __restrict__ r_out, int N) {
  constexpr int DOUT = 64;
  constexpr int NTT = 4;
  constexpr int SK = 72;
  __shared__ short Wt[2 * DOUT * SK];
  const int tid = threadIdx.x;
  stage_weights<DOUT, SK>(Wt, Wl, Wr, tid);
  __syncthreads();

  const int wv = tid >> 6, lane = tid & 63;
  const int q = lane >> 4, m = lane & 15;
  const int row = blockIdx.x * 64 + wv * 16 + m;
  const int rowc = row < N ? row : N - 1;
  const float* xp = &x[(size_t)rowc * 64];
  float4 f0 = *(const float4*)&xp[q * 8];
  float4 f1 = *(const float4*)&xp[q * 8 + 4];
  float4 f2 = *(const float4*)&xp[32 + q * 8];
  float4 f3 = *(const float4*)&xp[32 + q * 8 + 4];
  s16x8 a0, a1;
  a0[0] = (short)f2bf(f0.x); a0[1] = (short)f2bf(f0.y);
  a0[2] = (short)f2bf(f0.z); a0[3] = (short)f2bf(f0.w);
  a0[4] = (short)f2bf(f1.x); a0[5] = (short)f2bf(f1.y);
  a0[6] = (short)f2bf(f1.z); a0[7] = (short)f2bf(f1.w);
  a1[0] = (short)f2bf(f2.x); a1[1] = (short)f2bf(f2.y);
  a1[2] = (short)f2bf(f2.z); a1[3] = (short)f2bf(f2.w);
  a1[4] = (short)f2bf(f3.x); a1[5] = (short)f2bf(f3.y);
  a1[6] = (short)f2bf(f3.z); a1[7] = (short)f2bf(f3.w);

  f32x4 acc[2 * NTT];
#pragma unroll
  for (int c = 0; c < 2 * NTT; ++c) acc[c] = (f32x4){0.f, 0.f, 0.f, 0.f};
#pragma unroll
  for (int c = 0; c < 2 * NTT; ++c) {
    const short* wp = &Wt[(c * 16 + m) * SK];
    s16x8 b0 = *(const s16x8*)&wp[q * 8];
    s16x8 b1 = *(const s16x8*)&wp[32 + q * 8];
    acc[c] = __builtin_amdgcn_mfma_f32_16x16x32_bf16(a0, b0, acc[c], 0, 0, 0);
    acc[c] = __builtin_amdgcn_mfma_f32_16x16x32_bf16(a1, b1, acc[c], 0, 0, 0);
  }

  const int orow = blockIdx.x * 64 + wv * 16 + q * 4;
#pragma unroll
  for (int c = 0; c < NTT; ++c) {
#pragma unroll
    for (int i = 0; i < 4; ++i) {
      int r_ = orow + i;
      if (r_ < N) t_out[(size_t)r_ * DOUT + c * 16 + m] = f2fp8(acc[c][i]);
    }
  }
#pragma unroll
  for (int c = 0; c < NTT; ++c) {
    float bv = bias[c * 16 + m];
#pragma unroll
    for (int i = 0; i < 4; ++i) {
      int r_ = orow + i;
      if (r_ < N) r_out[(size_t)r_ * DOUT + c * 16 + m] = acc[NTT + c][i] + bv;
    }
  }
}

// ---------------- mid/final MFMA dual GEMM, bf16 input --------------------
// TFP8: t out fp8 (layer 1) else bf16 (layer 2).

template <int DOUT, bool TFP8>
__global__ __launch_bounds__(256) void gemm_mfma(const unsigned short* __restrict__ Hm,
                                                 const float* __restrict__ Wl,
                                                 const float* __restrict__ Wr,
                                                 const float* __restrict__ bias,
                                                 void* __restrict__ t_out,
                                                 float* __restrict__ r_out, int N) {
  constexpr int NTT = DOUT / 16;
  constexpr int SK = 72;
  __shared__ short Wt[2 * DOUT * SK];
  const int tid = threadIdx.x;
  stage_weights<DOUT, SK>(Wt, Wl, Wr, tid);
  __syncthreads();

  const int wv = tid >> 6, lane = tid & 63;
  const int q = lane >> 4, m = lane & 15;
  const int row = blockIdx.x * 64 + wv * 16 + m;
  const int rowc = row < N ? row : N - 1;
  const s16x8 a0 = *(const s16x8*)&Hm[(size_t)rowc * 64 + q * 8];
  const s16x8 a1 = *(const s16x8*)&Hm[(size_t)rowc * 64 + 32 + q * 8];

  f32x4 acc[2 * NTT];
#pragma unroll
  for (int c = 0; c < 2 * NTT; ++c) acc[c] = (f32x4){0.f, 0.f, 0.f, 0.f};
#pragma unroll
  for (int c = 0; c < 2 * NTT; ++c) {
    const short* wp = &Wt[(c * 16 + m) * SK];
    s16x8 b0 = *(const s16x8*)&wp[q * 8];
    s16x8 b1 = *(const s16x8*)&wp[32 + q * 8];
    acc[c] = __builtin_amdgcn_mfma_f32_16x16x32_bf16(a0, b0, acc[c], 0, 0, 0);
    acc[c] = __builtin_amdgcn_mfma_f32_16x16x32_bf16(a1, b1, acc[c], 0, 0, 0);
  }

  const int orow = blockIdx.x * 64 + wv * 16 + q * 4;
#pragma unroll
  for (int c = 0; c < NTT; ++c) {
#pragma unroll
    for (int i = 0; i < 4; ++i) {
      int r_ = orow + i;
      if (r_ < N) {
        if (TFP8)
          ((unsigned char*)t_out)[(size_t)r_ * DOUT + c * 16 + m] = f2fp8(acc[c][i]);
        else
          ((unsigned short*)t_out)[(size_t)r_ * DOUT + c * 16 + m] = f2bf(acc[c][i]);
      }
    }
  }
#pragma unroll
  for (int c = 0; c < NTT; ++c) {
    float bv = bias[c * 16 + m];
#pragma unroll
    for (int i = 0; i < 4; ++i) {
      int r_ = orow + i;
      if (r_ < N) r_out[(size_t)r_ * DOUT + c * 16 + m] = acc[NTT + c][i] + bv;
    }
  }
}

// ------ gather (fp8 t): h = bf16(elu(deg_inv * sum t[src] + r)) -----------
// 8 lanes per node, uint2/lane = 8 fp8 features; one row = 64B = 1 line,
// fully coalesced. 8-edge unroll for MLP. HW cvt_pk_f32_fp8 decode.

__global__ __launch_bounds__(256) void gather_fp8(const uint2* __restrict__ t,
                                                  const float* __restrict__ r,
                                                  const float* __restrict__ deg_inv,
                                                  const int* __restrict__ rowstart,
                                                  const int* __restrict__ degarr,
                                                  const int* __restrict__ colidx,
                                                  unsigned short* __restrict__ Xout,
                                                  int N) {
  int node = blockIdx.x * 32 + (threadIdx.x >> 3);
  int lane = threadIdx.x & 7;
  if (node >= N) return;
  int b = rowstart[node];
  int e = b + degarr[node];
  float s[8];
#pragma unroll
  for (int k = 0; k < 8; ++k) s[k] = 0.f;
  int i = b;
  for (; i + 8 <= e; i += 8) {
    uint2 v[8];
#pragma unroll
    for (int j = 0; j < 8; ++j)
      v[j] = t[(size_t)colidx[i + j] * 8 + lane];
#pragma unroll
    for (int j = 0; j < 8; ++j) {
      f32x2 p0 = __builtin_amdgcn_cvt_pk_f32_fp8((int)v[j].x, false);
      f32x2 p1 = __builtin_amdgcn_cvt_pk_f32_fp8((int)v[j].x, true);
      f32x2 p2 = __builtin_amdgcn_cvt_pk_f32_fp8((int)v[j].y, false);
      f32x2 p3 = __builtin_amdgcn_cvt_pk_f32_fp8((int)v[j].y, true);
      s[0] += p0[0]; s[1] += p0[1]; s[2] += p1[0]; s[3] += p1[1];
      s[4] += p2[0]; s[5] += p2[1]; s[6] += p3[0]; s[7] += p3[1];
    }
  }
  for (; i < e; ++i) {
    uint2 v = t[(size_t)colidx[i] * 8 + lane];
    f32x2 p0 = __builtin_amdgcn_cvt_pk_f32_fp8((int)v.x, false);
    f32x2 p1 = __builtin_amdgcn_cvt_pk_f32_fp8((int)v.x, true);
    f32x2 p2 = __builtin_amdgcn_cvt_pk_f32_fp8((int)v.y, false);
    f32x2 p3 = __builtin_amdgcn_cvt_pk_f32_fp8((int)v.y, true);
    s[0] += p0[0]; s[1] += p0[1]; s[2] += p1[0]; s[3] += p1[1];
    s[4] += p2[0]; s[5] += p2[1]; s[6] += p3[0]; s[7] += p3[1];
  }
  float dv = deg_inv[node];
  const float* rp = &r[(size_t)node * 64 + lane * 8];
  float4 r0 = *(const float4*)&rp[0];
  float4 r1 = *(const float4*)&rp[4];
  float a[8];
  a[0] = s[0] * dv + r0.x; a[1] = s[1] * dv + r0.y;
  a[2] = s[2] * dv + r0.z; a[3] = s[3] * dv + r0.w;
  a[4] = s[4] * dv + r1.x; a[5] = s[5] * dv + r1.y;
  a[6] = s[6] * dv + r1.z; a[7] = s[7] * dv + r1.w;
  s16x8 hv;
#pragma unroll
  for (int k = 0; k < 8; ++k) {
    float ak = a[k] > 0.f ? a[k] : (expf(a[k]) - 1.f);
    hv[k] = (short)f2bf(ak);
  }
  *(s16x8*)&Xout[(size_t)node * 64 + lane * 8] = hv;
}

// ------ final gather: out = deg_inv * sum t2[src] + r[dst], t2 bf16 -------

__global__ __launch_bounds__(256) void gather_out(const uint2* __restrict__ t,
                                                  const float* __restrict__ r,
                                                  const float* __restrict__ deg_inv,
                                                  const int* __restrict__ rowstart,
                                                  const int* __restrict__ degarr,
                                                  const int* __restrict__ colidx,
                                                  float* __restrict__ out, int N) {
  constexpr int L = 8;                 // uint2 lanes per node
  int node = blockIdx.x * 32 + threadIdx.x / L;
  int lane = threadIdx.x & (L - 1);
  if (node >= N) return;
  int b = rowstart[node];
  int e = b + degarr[node];
  float s0 = 0.f, s1 = 0.f, s2 = 0.f, s3 = 0.f;
  int i = b;
  for (; i + 8 <= e; i += 8) {
    uint2 v[8];
#pragma unroll
    for (int j = 0; j < 8; ++j)
      v[j] = t[(size_t)colidx[i + j] * L + lane];
#pragma unroll
    for (int j = 0; j < 8; ++j) {
      s0 += bf2f((unsigned short)(v[j].x & 0xFFFFu));
      s1 += bf2f((unsigned short)(v[j].x >> 16));
      s2 += bf2f((unsigned short)(v[j].y & 0xFFFFu));
      s3 += bf2f((unsigned short)(v[j].y >> 16));
    }
  }
  for (; i < e; ++i) {
    uint2 v = t[(size_t)colidx[i] * L + lane];
    s0 += bf2f((unsigned short)(v.x & 0xFFFFu));
    s1 += bf2f((unsigned short)(v.x >> 16));
    s2 += bf2f((unsigned short)(v.y & 0xFFFFu));
    s3 += bf2f((unsigned short)(v.y >> 16));
  }
  float dv = deg_inv[node];
  float4 rv = *(const float4*)&r[(size_t)node * 32 + 4 * lane];
  *(float4*)&out[(size_t)node * 32 + 4 * lane] =
      make_float4(s0 * dv + rv.x, s1 * dv + rv.y, s2 * dv + rv.z, s3 * dv + rv.w);
}

// ---------------- launch ----------------

extern "C" void kernel_launch(void* const* d_in, const int* in_sizes, int n_in,
                              void* d_out, int out_size, void* d_ws, size_t ws_size,
                              hipStream_t stream) {
  const float* x   = (const float*)d_in[0];
  const int*   ei  = (const int*)d_in[1];
  const float* Wl0 = (const float*)d_in[2];
  const float* Wr0 = (const float*)d_in[3];
  const float* b0  = (const float*)d_in[4];
  const float* Wl1 = (const float*)d_in[5];
  const float* Wr1 = (const float*)d_in[6];
  const float* b1  = (const float*)d_in[7];
  const float* Wl2 = (const float*)d_in[8];
  const float* Wr2 = (const float*)d_in[9];
  const float* b2  = (const float*)d_in[10];
  float* out = (float*)d_out;

  const int N = in_sizes[0] / 64;   // 100000
  const int E = in_sizes[1] / 2;    // 1600000
  const int* srcv = ei;
  const int* dstv = ei + E;
  const int NSB = (N + SBW - 1) >> LOGSBW;   // 391

  auto al = [](size_t v) { return (v + 255) & ~(size_t)255; };
  char* w = (char*)d_ws;
  size_t oBcur = 0;
  size_t oRow  = oBcur + al(4 * (size_t)NSB);
  size_t oDeg  = oRow + al(4 * (size_t)N);
  size_t oDinv = oDeg + al(4 * (size_t)N);
  size_t oBin  = oDinv + al(4 * (size_t)N);
  size_t oCol  = oBin + al(4 * (size_t)NSB * CAPS);
  size_t oP8   = oCol + al(4 * (size_t)NSB * CAPS);
  size_t oP16  = oP8 + al((size_t)N * 64);        // fp8 t buffer
  size_t oX    = oP16 + al(2 * (size_t)N * 32);   // bf16 t2 buffer
  size_t oR    = oX + al(2 * (size_t)N * 64);     // bf16 h buffer
  // total = oR + 4*N*64  (~73 MiB)

  int*            bcur     = (int*)(w + oBcur);
  int*            rowstart = (int*)(w + oRow);
  int*            degarr   = (int*)(w + oDeg);
  float*          deg_inv  = (float*)(w + oDinv);
  unsigned*       coarse   = (unsigned*)(w + oBin);
  int*            colidx   = (int*)(w + oCol);
  unsigned char*  P8       = (unsigned char*)(w + oP8);   // fp8 t0/t1
  unsigned short* P16      = (unsigned short*)(w + oP16); // bf16 t2
  unsigned short* X        = (unsigned short*)(w + oX);   // bf16 h
  float*          R        = (float*)(w + oR);            // fp32 r

  hipMemsetAsync(bcur, 0, (size_t)NSB * 4, stream);

  int bbl = (E + CHK - 1) / CHK;   // 782
  bin_coarse<<<bbl, 256, 0, stream>>>(srcv, dstv, bcur, coarse, NSB, E);
  super_csr<<<NSB, 256, 0, stream>>>(coarse, bcur, rowstart, degarr, deg_inv, colidx, N);

  int gb = (N + 63) / 64;          // 1563
  int ggb = (N + 31) / 32;         // 3125
  // layer 0: x -> t0 (fp8 P8), r0 (R)
  gemm0_mfma<<<gb, 256, 0, stream>>>(x, Wl0, Wr0, b0, P8, R, N);
  gather_fp8<<<ggb, 256, 0, stream>>>((const uint2*)P8, R, deg_inv, rowstart,
                                      degarr, colidx, X, N);
  // layer 1: X -> t1 (fp8 P8), r1 (R)
  gemm_mfma<64, true><<<gb, 256, 0, stream>>>(X, Wl1, Wr1, b1, P8, R, N);
  gather_fp8<<<ggb, 256, 0, stream>>>((const uint2*)P8, R, deg_inv, rowstart,
                                      degarr, colidx, X, N);
  // layer 2: X -> t2 (bf16 P16), r2 (R, [N][32])
  gemm_mfma<32, false><<<gb, 256, 0, stream>>>(X, Wl2, Wr2, b2, P16, R, N);
  gather_out<<<ggb, 256, 0, stream>>>((const uint2*)P16, R, deg_inv, rowstart,
                                      degarr, colidx, out, N);
}

// Round 12
// 285.824 us; speedup vs baseline: 1.1071x; 1.1071x over previous
//
#include <hip/hip_runtime.h>
#include <cstdint>
#include <cstddef>

// GraphSAGE 3-layer, N=100000 nodes, E=1600000 edges, dims 64->64->64->32.
// Transform-then-aggregate; padded CSR via 256-node super-buckets (2 kernels);
// weights pre-swizzled ONCE into MFMA B-fragment layout (stage_w) so the
// per-layer dual GEMMs (t=h@Wl bf16, r=h@Wr+b fp32, mfma_f32_16x16x32_bf16)
// are LDS-free and barrier-free pure streams; bf16 gathers (16 lanes/node,
// uint2/lane, 8-edge unroll) accumulate fp32.
// R4: LDS-atomic aggregation is 12x slower than CSR gather — don't revisit.
// R6: short scatter runs -> 64B-line write amplification.
// R7: 196-block bin_coarse latency-bound; LDS-cache + 782 blocks.
// R10: gather+GEMM fusion halves occupancy, couples imbalance — keep split.
// R11 post-mortem: GEMMs were ~40us latency-bound on per-block LDS weight
// staging + barrier (45us, VALU 7%, 1TB/s); fp8 t doubled absmax for a net
// regression — reverted. Fix: global pre-swizzled B-frags, no LDS, no barrier.

constexpr int SBW = 256;     // dst nodes per super-bucket
constexpr int LOGSBW = 8;
constexpr int CAPS = 4608;   // super capacity; mean 4096, sigma ~64 (+8σ)
constexpr int CHK = 2048;    // edges per bin_coarse block -> 782 blocks

typedef __attribute__((ext_vector_type(8))) short s16x8;
typedef __attribute__((ext_vector_type(4))) float f32x4;

__device__ inline unsigned short f2bf(float f) {
  unsigned u = __builtin_bit_cast(unsigned, f);
  u += 0x7FFFu + ((u >> 16) & 1u);          // round-to-nearest-even
  return (unsigned short)(u >> 16);
}
__device__ inline float bf2f(unsigned short b) {
  unsigned u = ((unsigned)b) << 16;
  return __builtin_bit_cast(float, u);
}

// ---------------- pass 1: coarse bin into 256-node super-buckets ----------

__global__ __launch_bounds__(256) void bin_coarse(const int* __restrict__ src,
                                                  const int* __restrict__ dst,
                                                  int* __restrict__ bcur,
                                                  unsigned int* __restrict__ coarse,
                                                  int NSB, int E) {
  __shared__ int h[512];
  __shared__ unsigned ed[CHK];
  __shared__ short sb[CHK];
  const int tid = threadIdx.x;
  for (int i = tid; i < NSB; i += 256) h[i] = 0;
  __syncthreads();
  const int e0 = blockIdx.x * CHK;
  const int e1 = min(E, e0 + CHK);
  for (int e = e0 + tid; e < e1; e += 256) {
    int d = dst[e];
    int s = src[e];
    int b = d >> LOGSBW;
    ed[e - e0] = (unsigned)s | ((unsigned)(d & (SBW - 1)) << 17);
    sb[e - e0] = (short)b;
    atomicAdd(&h[b], 1);
  }
  __syncthreads();
  for (int i = tid; i < NSB; i += 256) {
    int c = h[i];
    h[i] = c ? (i * CAPS + atomicAdd(&bcur[i], c)) : 0;  // slot -> abs cursor
  }
  __syncthreads();
  const int n = e1 - e0;
  for (int k = tid; k < n; k += 256) {
    int b = sb[k];
    int pos = atomicAdd(&h[b], 1);
    if (pos < (b + 1) * CAPS)                 // overflow guard (never taken)
      coarse[pos] = ed[k];
  }
}

// ---------------- pass 2: per-super count/scan/sort -> padded CSR ---------

__global__ __launch_bounds__(256) void super_csr(const unsigned int* __restrict__ coarse,
                                                 const int* __restrict__ bcur,
                                                 int* __restrict__ rowstart,
                                                 int* __restrict__ degarr,
                                                 float* __restrict__ deg_inv,
                                                 int* __restrict__ colidx,
                                                 int N) {
  __shared__ int cnt[SBW];
  __shared__ int sc[SBW];
  __shared__ int cur[SBW];
  const int b = blockIdx.x;
  const int tid = threadIdx.x;
  cnt[tid] = 0;
  __syncthreads();
  const int ec = min(bcur[b], CAPS);
  const int base = b * CAPS;
  for (int e = tid; e < ec; e += 256)
    atomicAdd(&cnt[coarse[base + e] >> 17], 1);
  __syncthreads();
  int v = cnt[tid];
  sc[tid] = v;
  __syncthreads();
  for (int off = 1; off < SBW; off <<= 1) {
    int y = sc[tid];
    if (tid >= off) y += sc[tid - off];
    __syncthreads();
    sc[tid] = y;
    __syncthreads();
  }
  int ex = sc[tid] - v;                       // exclusive prefix
  cur[tid] = ex;
  int gn = b * SBW + tid;
  if (gn < N) {
    rowstart[gn] = base + ex;
    degarr[gn] = v;
    deg_inv[gn] = 1.0f / (float)(v > 1 ? v : 1);
  }
  __syncthreads();
  for (int e = tid; e < ec; e += 256) {
    unsigned p = coarse[base + e];
    int dl = (int)(p >> 17);
    int s = (int)(p & 0x1FFFFu);
    int l = atomicAdd(&cur[dl], 1);
    colidx[base + l] = s;
  }
}

// ---------------- one-shot weight swizzle into MFMA B-frag layout ---------
// Per layer: 2*NTT tiles (Wl tiles then Wr tiles); per tile 2 planes (k<32,
// k>=32); per plane 64 lanes x 8 bf16. Element: lane l=(q,m), j ->
// W[k = plane*32 + q*8 + j][col = c*16 + m], bf16.
// Layer short offsets: L0=0, L1=8192, L2=16384 (total 20480 shorts = 40KB).
// gemm fetch: frag = Wsw[layer_off + (c*2+plane)*512 + lane*8 .. +8]
// (lane-contiguous 16B => 1KB fully-coalesced, L2-resident).

__global__ __launch_bounds__(256) void stage_w(const float* __restrict__ Wl0,
                                               const float* __restrict__ Wr0,
                                               const float* __restrict__ Wl1,
                                               const float* __restrict__ Wr1,
                                               const float* __restrict__ Wl2,
                                               const float* __restrict__ Wr2,
                                               unsigned short* __restrict__ Wsw) {
  int g = blockIdx.x * 256 + threadIdx.x;      // u32 index
  if (g >= 10240) return;
  int s = g * 2;                               // short index (j even)
  int layer, off;
  if (s < 8192)       { layer = 0; off = 0; }
  else if (s < 16384) { layer = 1; off = 8192; }
  else                { layer = 2; off = 16384; }
  int t = s - off;
  int D = (layer == 2) ? 32 : 64;
  int NTT = D / 16;
  int tt = t >> 10;
  int rem = t & 1023;
  int plane = rem >> 9;
  int rem2 = rem & 511;
  int lane = rem2 >> 3;
  int j = rem2 & 7;
  int q = lane >> 4, m = lane & 15;
  int k = plane * 32 + q * 8 + j;
  const float* W;
  int c;
  if (tt < NTT) {
    c = tt;
    W = (layer == 0) ? Wl0 : (layer == 1) ? Wl1 : Wl2;
  } else {
    c = tt - NTT;
    W = (layer == 0) ? Wr0 : (layer == 1) ? Wr1 : Wr2;
  }
  int col = c * 16 + m;
  unsigned lo = f2bf(W[k * D + col]);
  unsigned hi = f2bf(W[(k + 1) * D + col]);
  *(unsigned*)&Wsw[s] = lo | (hi << 16);
}

// ---------------- layer-0 MFMA dual GEMM, fp32 input, LDS-free ------------
// C/D layout: col=lane&15, row=(lane>>4)*4+reg (m89-verified).

__global__ __launch_bounds__(256) void gemm0_mfma(const float* __restrict__ x,
                                                  const unsigned short* __restrict__ Wf,
                                                  const float* __restrict__ bias,
                                                  unsigned short* __restrict__ t_out,
                                                  float* __restrict__ r_out, int N) {
  constexpr int DOUT = 64;
  constexpr int NTT = 4;
  const int tid = threadIdx.x;
  const int wv = tid >> 6, lane = tid & 63;
  const int q = lane >> 4, m = lane & 15;
  const int row = blockIdx.x * 64 + wv * 16 + m;
  const int rowc = row < N ? row : N - 1;
  const float* xp = &x[(size_t)rowc * 64];
  float4 f0 = *(const float4*)&xp[q * 8];
  float4 f1 = *(const float4*)&xp[q * 8 + 4];
  float4 f2 = *(const float4*)&xp[32 + q * 8];
  float4 f3 = *(const float4*)&xp[32 + q * 8 + 4];
  s16x8 a0, a1;
  a0[0] = (short)f2bf(f0.x); a0[1] = (short)f2bf(f0.y);
  a0[2] = (short)f2bf(f0.z); a0[3] = (short)f2bf(f0.w);
  a0[4] = (short)f2bf(f1.x); a0[5] = (short)f2bf(f1.y);
  a0[6] = (short)f2bf(f1.z); a0[7] = (short)f2bf(f1.w);
  a1[0] = (short)f2bf(f2.x); a1[1] = (short)f2bf(f2.y);
  a1[2] = (short)f2bf(f2.z); a1[3] = (short)f2bf(f2.w);
  a1[4] = (short)f2bf(f3.x); a1[5] = (short)f2bf(f3.y);
  a1[6] = (short)f2bf(f3.z); a1[7] = (short)f2bf(f3.w);

  f32x4 acc[2 * NTT];
#pragma unroll
  for (int c = 0; c < 2 * NTT; ++c) acc[c] = (f32x4){0.f, 0.f, 0.f, 0.f};
#pragma unroll
  for (int c = 0; c < 2 * NTT; ++c) {
    s16x8 b0 = *(const s16x8*)&Wf[(c * 2 + 0) * 512 + lane * 8];
    s16x8 b1 = *(const s16x8*)&Wf[(c * 2 + 1) * 512 + lane * 8];
    acc[c] = __builtin_amdgcn_mfma_f32_16x16x32_bf16(a0, b0, acc[c], 0, 0, 0);
    acc[c] = __builtin_amdgcn_mfma_f32_16x16x32_bf16(a1, b1, acc[c], 0, 0, 0);
  }

  const int orow = blockIdx.x * 64 + wv * 16 + q * 4;
#pragma unroll
  for (int c = 0; c < NTT; ++c) {
#pragma unroll
    for (int i = 0; i < 4; ++i) {
      int r_ = orow + i;
      if (r_ < N) t_out[(size_t)r_ * DOUT + c * 16 + m] = f2bf(acc[c][i]);
    }
  }
#pragma unroll
  for (int c = 0; c < NTT; ++c) {
    float bv = bias[c * 16 + m];
#pragma unroll
    for (int i = 0; i < 4; ++i) {
      int r_ = orow + i;
      if (r_ < N) r_out[(size_t)r_ * DOUT + c * 16 + m] = acc[NTT + c][i] + bv;
    }
  }
}

// ---------------- mid/final MFMA dual GEMM, bf16 input, LDS-free ----------

template <int DOUT>
__global__ __launch_bounds__(256) void gemm_mfma(const unsigned short* __restrict__ Hm,
                                                 const unsigned short* __restrict__ Wf,
                                                 const float* __restrict__ bias,
                                                 unsigned short* __restrict__ t_out,
                                                 float* __restrict__ r_out, int N) {
  constexpr int NTT = DOUT / 16;
  const int tid = threadIdx.x;
  const int wv = tid >> 6, lane = tid & 63;
  const int q = lane >> 4, m = lane & 15;
  const int row = blockIdx.x * 64 + wv * 16 + m;
  const int rowc = row < N ? row : N - 1;
  const s16x8 a0 = *(const s16x8*)&Hm[(size_t)rowc * 64 + q * 8];
  const s16x8 a1 = *(const s16x8*)&Hm[(size_t)rowc * 64 + 32 + q * 8];

  f32x4 acc[2 * NTT];
#pragma unroll
  for (int c = 0; c < 2 * NTT; ++c) acc[c] = (f32x4){0.f, 0.f, 0.f, 0.f};
#pragma unroll
  for (int c = 0; c < 2 * NTT; ++c) {
    s16x8 b0 = *(const s16x8*)&Wf[(c * 2 + 0) * 512 + lane * 8];
    s16x8 b1 = *(const s16x8*)&Wf[(c * 2 + 1) * 512 + lane * 8];
    acc[c] = __builtin_amdgcn_mfma_f32_16x16x32_bf16(a0, b0, acc[c], 0, 0, 0);
    acc[c] = __builtin_amdgcn_mfma_f32_16x16x32_bf16(a1, b1, acc[c], 0, 0, 0);
  }

  const int orow = blockIdx.x * 64 + wv * 16 + q * 4;
#pragma unroll
  for (int c = 0; c < NTT; ++c) {
#pragma unroll
    for (int i = 0; i < 4; ++i) {
      int r_ = orow + i;
      if (r_ < N) t_out[(size_t)r_ * DOUT + c * 16 + m] = f2bf(acc[c][i]);
    }
  }
#pragma unroll
  for (int c = 0; c < NTT; ++c) {
    float bv = bias[c * 16 + m];
#pragma unroll
    for (int i = 0; i < 4; ++i) {
      int r_ = orow + i;
      if (r_ < N) r_out[(size_t)r_ * DOUT + c * 16 + m] = acc[NTT + c][i] + bv;
    }
  }
}

// ------ gather: out = elu?(deg_inv * sum t[src] + r[dst]), t is bf16 ------
// DOUT/4 lanes per node; each lane owns 4 features via one uint2 (8 B) load
// per edge; 8-edge unroll => up to 32 row loads in flight per wave.
// BF16OUT: write bf16 h for the next layer's GEMM. Else fp32 out.

template <int DOUT, bool DO_ELU, bool BF16OUT>
__global__ __launch_bounds__(256) void gather_mean(const uint2* __restrict__ t,
                                                   const float* __restrict__ r,
                                                   const float* __restrict__ deg_inv,
                                                   const int* __restrict__ rowstart,
                                                   const int* __restrict__ degarr,
                                                   const int* __restrict__ colidx,
                                                   void* __restrict__ out, int N) {
  constexpr int L = DOUT / 4;                 // uint2 lanes per node: 16 or 8
  int node = blockIdx.x * (256 / L) + threadIdx.x / L;
  int lane = threadIdx.x & (L - 1);
  if (node >= N) return;
  int b = rowstart[node];
  int e = b + degarr[node];
  float s0 = 0.f, s1 = 0.f, s2 = 0.f, s3 = 0.f;
  int i = b;
  for (; i + 8 <= e; i += 8) {
    uint2 v[8];
#pragma unroll
    for (int j = 0; j < 8; ++j)
      v[j] = t[(size_t)colidx[i + j] * L + lane];
#pragma unroll
    for (int j = 0; j < 8; ++j) {
      s0 += bf2f((unsigned short)(v[j].x & 0xFFFFu));
      s1 += bf2f((unsigned short)(v[j].x >> 16));
      s2 += bf2f((unsigned short)(v[j].y & 0xFFFFu));
      s3 += bf2f((unsigned short)(v[j].y >> 16));
    }
  }
  for (; i < e; ++i) {
    uint2 v = t[(size_t)colidx[i] * L + lane];
    s0 += bf2f((unsigned short)(v.x & 0xFFFFu));
    s1 += bf2f((unsigned short)(v.x >> 16));
    s2 += bf2f((unsigned short)(v.y & 0xFFFFu));
    s3 += bf2f((unsigned short)(v.y >> 16));
  }
  float dv = deg_inv[node];
  float4 rv = *(const float4*)&r[(size_t)node * DOUT + 4 * lane];
  float a0 = s0 * dv + rv.x;
  float a1 = s1 * dv + rv.y;
  float a2 = s2 * dv + rv.z;
  float a3 = s3 * dv + rv.w;
  if (DO_ELU) {
    a0 = a0 > 0.f ? a0 : (expf(a0) - 1.f);
    a1 = a1 > 0.f ? a1 : (expf(a1) - 1.f);
    a2 = a2 > 0.f ? a2 : (expf(a2) - 1.f);
    a3 = a3 > 0.f ? a3 : (expf(a3) - 1.f);
  }
  if (BF16OUT) {
    ushort4 hv;
    hv.x = f2bf(a0); hv.y = f2bf(a1); hv.z = f2bf(a2); hv.w = f2bf(a3);
    *(ushort4*)&((unsigned short*)out)[(size_t)node * DOUT + 4 * lane] = hv;
  } else {
    *(float4*)&((float*)out)[(size_t)node * DOUT + 4 * lane] =
        make_float4(a0, a1, a2, a3);
  }
}

// ---------------- launch ----------------

extern "C" void kernel_launch(void* const* d_in, const int* in_sizes, int n_in,
                              void* d_out, int out_size, void* d_ws, size_t ws_size,
                              hipStream_t stream) {
  const float* x   = (const float*)d_in[0];
  const int*   ei  = (const int*)d_in[1];
  const float* Wl0 = (const float*)d_in[2];
  const float* Wr0 = (const float*)d_in[3];
  const float* b0  = (const float*)d_in[4];
  const float* Wl1 = (const float*)d_in[5];
  const float* Wr1 = (const float*)d_in[6];
  const float* b1  = (const float*)d_in[7];
  const float* Wl2 = (const float*)d_in[8];
  const float* Wr2 = (const float*)d_in[9];
  const float* b2  = (const float*)d_in[10];
  float* out = (float*)d_out;

  const int N = in_sizes[0] / 64;   // 100000
  const int E = in_sizes[1] / 2;    // 1600000
  const int* srcv = ei;
  const int* dstv = ei + E;
  const int NSB = (N + SBW - 1) >> LOGSBW;   // 391

  auto al = [](size_t v) { return (v + 255) & ~(size_t)255; };
  char* w = (char*)d_ws;
  size_t oBcur = 0;
  size_t oRow  = oBcur + al(4 * (size_t)NSB);
  size_t oDeg  = oRow + al(4 * (size_t)N);
  size_t oDinv = oDeg + al(4 * (size_t)N);
  size_t oWsw  = oDinv + al(4 * (size_t)N);
  size_t oBin  = oWsw + al(2 * 20480);
  size_t oCol  = oBin + al(4 * (size_t)NSB * CAPS);
  size_t oP    = oCol + al(4 * (size_t)NSB * CAPS);
  size_t oX    = oP + al(2 * (size_t)N * 64);   // bf16 t buffer
  size_t oR    = oX + al(2 * (size_t)N * 64);   // bf16 h buffer
  // total = oR + 4*N*64  (~67 MiB)

  int*            bcur     = (int*)(w + oBcur);
  int*            rowstart = (int*)(w + oRow);
  int*            degarr   = (int*)(w + oDeg);
  float*          deg_inv  = (float*)(w + oDinv);
  unsigned short* Wsw      = (unsigned short*)(w + oWsw); // swizzled weights
  unsigned*       coarse   = (unsigned*)(w + oBin);
  int*            colidx   = (int*)(w + oCol);
  unsigned short* P        = (unsigned short*)(w + oP);   // bf16 t buffer
  unsigned short* X        = (unsigned short*)(w + oX);   // bf16 h buffer
  float*          R        = (float*)(w + oR);            // fp32 r buffer

  hipMemsetAsync(bcur, 0, (size_t)NSB * 4, stream);

  stage_w<<<40, 256, 0, stream>>>(Wl0, Wr0, Wl1, Wr1, Wl2, Wr2, Wsw);
  int bbl = (E + CHK - 1) / CHK;   // 782
  bin_coarse<<<bbl, 256, 0, stream>>>(srcv, dstv, bcur, coarse, NSB, E);
  super_csr<<<NSB, 256, 0, stream>>>(coarse, bcur, rowstart, degarr, deg_inv, colidx, N);

  int gb = (N + 63) / 64;   // 1563
  // layer 0: fp32 x -> t0 (P), r0 (R)
  gemm0_mfma<<<gb, 256, 0, stream>>>(x, Wsw, b0, P, R, N);
  gather_mean<64, true, true><<<(N + 15) / 16, 256, 0, stream>>>(
      (const uint2*)P, R, deg_inv, rowstart, degarr, colidx, X, N);
  // layer 1: X -> t1 (P), r1 (R)
  gemm_mfma<64><<<gb, 256, 0, stream>>>(X, Wsw + 8192, b1, P, R, N);
  gather_mean<64, true, true><<<(N + 15) / 16, 256, 0, stream>>>(
      (const uint2*)P, R, deg_inv, rowstart, degarr, colidx, X, N);
  // layer 2: X -> t2 (P, [N][32]), r2 (R, [N][32])
  gemm_mfma<32><<<gb, 256, 0, stream>>>(X, Wsw + 16384, b2, P, R, N);
  gather_mean<32, false, false><<<(N + 31) / 32, 256, 0, stream>>>(
      (const uint2*)P, R, deg_inv, rowstart, degarr, colidx, out, N);
}

// Round 13
// 266.465 us; speedup vs baseline: 1.1875x; 1.0727x over previous
//
#include <hip/hip_runtime.h>
#include <cstdint>
#include <cstddef>

// GraphSAGE 3-layer, N=100000 nodes, E=1600000 edges, dims 64->64->64->32.
// Transform-then-aggregate; padded CSR via 256-node super-buckets (2 kernels);
// weights pre-swizzled once into MFMA B-frag layout (stage_w); per-layer dual
// GEMMs (t=h@Wl, r=h@Wr+b fp32, mfma_f32_16x16x32_bf16) are LDS-free and
// barrier-free; t for layers 0/1 stored fp8 e4m3 (row = 64B = 1 line) to
// halve the gather's cross-XCD fetch floor; t2 bf16; r always fp32.
// R4: LDS-atomic aggregation is 12x slower than CSR gather — don't revisit.
// R6: short scatter runs -> 64B-line write amplification.
// R7: 196-block bin_coarse latency-bound; LDS-cache + 782 blocks.
// R10: gather+GEMM fusion halves occupancy, couples imbalance — keep split.
// R12 post-mortem: R11's "40us latency-bound GEMM" was an artifact of R11's
// broken (512B-strided) weight staging; R9/R12 GEMMs are ~12-15us either way.
// R11's real win was the fp8 gather (~-45us, absmax 0.066 passes) — this
// round combines R12 GEMMs + R11 fp8 gathers.

constexpr int SBW = 256;     // dst nodes per super-bucket
constexpr int LOGSBW = 8;
constexpr int CAPS = 4608;   // super capacity; mean 4096, sigma ~64 (+8σ)
constexpr int CHK = 2048;    // edges per bin_coarse block -> 782 blocks

typedef __attribute__((ext_vector_type(8))) short s16x8;
typedef __attribute__((ext_vector_type(4))) float f32x4;
typedef __attribute__((ext_vector_type(2))) float f32x2;

__device__ inline unsigned short f2bf(float f) {
  unsigned u = __builtin_bit_cast(unsigned, f);
  u += 0x7FFFu + ((u >> 16) & 1u);          // round-to-nearest-even
  return (unsigned short)(u >> 16);
}
__device__ inline float bf2f(unsigned short b) {
  unsigned u = ((unsigned)b) << 16;
  return __builtin_bit_cast(float, u);
}
__device__ inline unsigned char f2fp8(float f) {
  int p = __builtin_amdgcn_cvt_pk_fp8_f32(f, f, 0, false);
  return (unsigned char)(p & 0xFF);
}

// ---------------- pass 1: coarse bin into 256-node super-buckets ----------

__global__ __launch_bounds__(256) void bin_coarse(const int* __restrict__ src,
                                                  const int* __restrict__ dst,
                                                  int* __restrict__ bcur,
                                                  unsigned int* __restrict__ coarse,
                                                  int NSB, int E) {
  __shared__ int h[512];
  __shared__ unsigned ed[CHK];
  __shared__ short sb[CHK];
  const int tid = threadIdx.x;
  for (int i = tid; i < NSB; i += 256) h[i] = 0;
  __syncthreads();
  const int e0 = blockIdx.x * CHK;
  const int e1 = min(E, e0 + CHK);
  for (int e = e0 + tid; e < e1; e += 256) {
    int d = dst[e];
    int s = src[e];
    int b = d >> LOGSBW;
    ed[e - e0] = (unsigned)s | ((unsigned)(d & (SBW - 1)) << 17);
    sb[e - e0] = (short)b;
    atomicAdd(&h[b], 1);
  }
  __syncthreads();
  for (int i = tid; i < NSB; i += 256) {
    int c = h[i];
    h[i] = c ? (i * CAPS + atomicAdd(&bcur[i], c)) : 0;  // slot -> abs cursor
  }
  __syncthreads();
  const int n = e1 - e0;
  for (int k = tid; k < n; k += 256) {
    int b = sb[k];
    int pos = atomicAdd(&h[b], 1);
    if (pos < (b + 1) * CAPS)                 // overflow guard (never taken)
      coarse[pos] = ed[k];
  }
}

// ---------------- pass 2: per-super count/scan/sort -> padded CSR ---------

__global__ __launch_bounds__(256) void super_csr(const unsigned int* __restrict__ coarse,
                                                 const int* __restrict__ bcur,
                                                 int* __restrict__ rowstart,
                                                 int* __restrict__ degarr,
                                                 float* __restrict__ deg_inv,
                                                 int* __restrict__ colidx,
                                                 int N) {
  __shared__ int cnt[SBW];
  __shared__ int sc[SBW];
  __shared__ int cur[SBW];
  const int b = blockIdx.x;
  const int tid = threadIdx.x;
  cnt[tid] = 0;
  __syncthreads();
  const int ec = min(bcur[b], CAPS);
  const int base = b * CAPS;
  for (int e = tid; e < ec; e += 256)
    atomicAdd(&cnt[coarse[base + e] >> 17], 1);
  __syncthreads();
  int v = cnt[tid];
  sc[tid] = v;
  __syncthreads();
  for (int off = 1; off < SBW; off <<= 1) {
    int y = sc[tid];
    if (tid >= off) y += sc[tid - off];
    __syncthreads();
    sc[tid] = y;
    __syncthreads();
  }
  int ex = sc[tid] - v;                       // exclusive prefix
  cur[tid] = ex;
  int gn = b * SBW + tid;
  if (gn < N) {
    rowstart[gn] = base + ex;
    degarr[gn] = v;
    deg_inv[gn] = 1.0f / (float)(v > 1 ? v : 1);
  }
  __syncthreads();
  for (int e = tid; e < ec; e += 256) {
    unsigned p = coarse[base + e];
    int dl = (int)(p >> 17);
    int s = (int)(p & 0x1FFFFu);
    int l = atomicAdd(&cur[dl], 1);
    colidx[base + l] = s;
  }
}

// ---------------- one-shot weight swizzle into MFMA B-frag layout ---------
// Per layer: 2*NTT tiles (Wl tiles then Wr tiles); per tile 2 planes (k<32,
// k>=32); per plane 64 lanes x 8 bf16: W[k=plane*32+q*8+j][col=c*16+m].
// Layer short offsets: L0=0, L1=8192, L2=16384. gemm fetch:
// frag = Wsw[off + (c*2+plane)*512 + lane*8 ..+8] (16B/lane, coalesced).

__global__ __launch_bounds__(256) void stage_w(const float* __restrict__ Wl0,
                                               const float* __restrict__ Wr0,
                                               const float* __restrict__ Wl1,
                                               const float* __restrict__ Wr1,
                                               const float* __restrict__ Wl2,
                                               const float* __restrict__ Wr2,
                                               unsigned short* __restrict__ Wsw) {
  int g = blockIdx.x * 256 + threadIdx.x;      // u32 index
  if (g >= 10240) return;
  int s = g * 2;                               // short index (j even)
  int layer, off;
  if (s < 8192)       { layer = 0; off = 0; }
  else if (s < 16384) { layer = 1; off = 8192; }
  else                { layer = 2; off = 16384; }
  int t = s - off;
  int D = (layer == 2) ? 32 : 64;
  int NTT = D / 16;
  int tt = t >> 10;
  int rem = t & 1023;
  int plane = rem >> 9;
  int rem2 = rem & 511;
  int lane = rem2 >> 3;
  int j = rem2 & 7;
  int q = lane >> 4, m = lane & 15;
  int k = plane * 32 + q * 8 + j;
  const float* W;
  int c;
  if (tt < NTT) {
    c = tt;
    W = (layer == 0) ? Wl0 : (layer == 1) ? Wl1 : Wl2;
  } else {
    c = tt - NTT;
    W = (layer == 0) ? Wr0 : (layer == 1) ? Wr1 : Wr2;
  }
  int col = c * 16 + m;
  unsigned lo = f2bf(W[k * D + col]);
  unsigned hi = f2bf(W[(k + 1) * D + col]);
  *(unsigned*)&Wsw[s] = lo | (hi << 16);
}

// ---------------- layer-0 MFMA dual GEMM, fp32 input, LDS-free ------------
// C/D layout: col=lane&15, row=(lane>>4)*4+reg (m89-verified). t out fp8.

__global__ __launch_bounds__(256) void gemm0_mfma(const float* __restrict__ x,
                                                  const unsigned short* __restrict__ Wf,
                                                  const float* __restrict__ bias,
                                                  unsigned char* __restrict__ t_out,
                                                  float* __restrict__ r_out, int N) {
  constexpr int DOUT = 64;
  constexpr int NTT = 4;
  const int tid = threadIdx.x;
  const int wv = tid >> 6, lane = tid & 63;
  const int q = lane >> 4, m = lane & 15;
  const int row = blockIdx.x * 64 + wv * 16 + m;
  const int rowc = row < N ? row : N - 1;
  const float* xp = &x[(size_t)rowc * 64];
  float4 f0 = *(const float4*)&xp[q * 8];
  float4 f1 = *(const float4*)&xp[q * 8 + 4];
  float4 f2 = *(const float4*)&xp[32 + q * 8];
  float4 f3 = *(const float4*)&xp[32 + q * 8 + 4];
  s16x8 a0, a1;
  a0[0] = (short)f2bf(f0.x); a0[1] = (short)f2bf(f0.y);
  a0[2] = (short)f2bf(f0.z); a0[3] = (short)f2bf(f0.w);
  a0[4] = (short)f2bf(f1.x); a0[5] = (short)f2bf(f1.y);
  a0[6] = (short)f2bf(f1.z); a0[7] = (short)f2bf(f1.w);
  a1[0] = (short)f2bf(f2.x); a1[1] = (short)f2bf(f2.y);
  a1[2] = (short)f2bf(f2.z); a1[3] = (short)f2bf(f2.w);
  a1[4] = (short)f2bf(f3.x); a1[5] = (short)f2bf(f3.y);
  a1[6] = (short)f2bf(f3.z); a1[7] = (short)f2bf(f3.w);

  f32x4 acc[2 * NTT];
#pragma unroll
  for (int c = 0; c < 2 * NTT; ++c) acc[c] = (f32x4){0.f, 0.f, 0.f, 0.f};
#pragma unroll
  for (int c = 0; c < 2 * NTT; ++c) {
    s16x8 b0 = *(const s16x8*)&Wf[(c * 2 + 0) * 512 + lane * 8];
    s16x8 b1 = *(const s16x8*)&Wf[(c * 2 + 1) * 512 + lane * 8];
    acc[c] = __builtin_amdgcn_mfma_f32_16x16x32_bf16(a0, b0, acc[c], 0, 0, 0);
    acc[c] = __builtin_amdgcn_mfma_f32_16x16x32_bf16(a1, b1, acc[c], 0, 0, 0);
  }

  const int orow = blockIdx.x * 64 + wv * 16 + q * 4;
#pragma unroll
  for (int c = 0; c < NTT; ++c) {
#pragma unroll
    for (int i = 0; i < 4; ++i) {
      int r_ = orow + i;
      if (r_ < N) t_out[(size_t)r_ * DOUT + c * 16 + m] = f2fp8(acc[c][i]);
    }
  }
#pragma unroll
  for (int c = 0; c < NTT; ++c) {
    float bv = bias[c * 16 + m];
#pragma unroll
    for (int i = 0; i < 4; ++i) {
      int r_ = orow + i;
      if (r_ < N) r_out[(size_t)r_ * DOUT + c * 16 + m] = acc[NTT + c][i] + bv;
    }
  }
}

// ---------------- mid/final MFMA dual GEMM, bf16 input, LDS-free ----------
// TFP8: t out fp8 (layer 1) else bf16 (layer 2).

template <int DOUT, bool TFP8>
__global__ __launch_bounds__(256) void gemm_mfma(const unsigned short* __restrict__ Hm,
                                                 const unsigned short* __restrict__ Wf,
                                                 const float* __restrict__ bias,
                                                 void* __restrict__ t_out,
                                                 float* __restrict__ r_out, int N) {
  constexpr int NTT = DOUT / 16;
  const int tid = threadIdx.x;
  const int wv = tid >> 6, lane = tid & 63;
  const int q = lane >> 4, m = lane & 15;
  const int row = blockIdx.x * 64 + wv * 16 + m;
  const int rowc = row < N ? row : N - 1;
  const s16x8 a0 = *(const s16x8*)&Hm[(size_t)rowc * 64 + q * 8];
  const s16x8 a1 = *(const s16x8*)&Hm[(size_t)rowc * 64 + 32 + q * 8];

  f32x4 acc[2 * NTT];
#pragma unroll
  for (int c = 0; c < 2 * NTT; ++c) acc[c] = (f32x4){0.f, 0.f, 0.f, 0.f};
#pragma unroll
  for (int c = 0; c < 2 * NTT; ++c) {
    s16x8 b0 = *(const s16x8*)&Wf[(c * 2 + 0) * 512 + lane * 8];
    s16x8 b1 = *(const s16x8*)&Wf[(c * 2 + 1) * 512 + lane * 8];
    acc[c] = __builtin_amdgcn_mfma_f32_16x16x32_bf16(a0, b0, acc[c], 0, 0, 0);
    acc[c] = __builtin_amdgcn_mfma_f32_16x16x32_bf16(a1, b1, acc[c], 0, 0, 0);
  }

  const int orow = blockIdx.x * 64 + wv * 16 + q * 4;
#pragma unroll
  for (int c = 0; c < NTT; ++c) {
#pragma unroll
    for (int i = 0; i < 4; ++i) {
      int r_ = orow + i;
      if (r_ < N) {
        if (TFP8)
          ((unsigned char*)t_out)[(size_t)r_ * DOUT + c * 16 + m] = f2fp8(acc[c][i]);
        else
          ((unsigned short*)t_out)[(size_t)r_ * DOUT + c * 16 + m] = f2bf(acc[c][i]);
      }
    }
  }
#pragma unroll
  for (int c = 0; c < NTT; ++c) {
    float bv = bias[c * 16 + m];
#pragma unroll
    for (int i = 0; i < 4; ++i) {
      int r_ = orow + i;
      if (r_ < N) r_out[(size_t)r_ * DOUT + c * 16 + m] = acc[NTT + c][i] + bv;
    }
  }
}

// ------ gather (fp8 t): h = bf16(elu(deg_inv * sum t[src] + r)) -----------
// 8 lanes per node, uint2/lane = 8 fp8 features; one row = 64B = 1 line,
// fully coalesced. 8-edge unroll for MLP. HW cvt_pk_f32_fp8 decode.

__global__ __launch_bounds__(256) void gather_fp8(const uint2* __restrict__ t,
                                                  const float* __restrict__ r,
                                                  const float* __restrict__ deg_inv,
                                                  const int* __restrict__ rowstart,
                                                  const int* __restrict__ degarr,
                                                  const int* __restrict__ colidx,
                                                  unsigned short* __restrict__ Xout,
                                                  int N) {
  int node = blockIdx.x * 32 + (threadIdx.x >> 3);
  int lane = threadIdx.x & 7;
  if (node >= N) return;
  int b = rowstart[node];
  int e = b + degarr[node];
  float s[8];
#pragma unroll
  for (int k = 0; k < 8; ++k) s[k] = 0.f;
  int i = b;
  for (; i + 8 <= e; i += 8) {
    uint2 v[8];
#pragma unroll
    for (int j = 0; j < 8; ++j)
      v[j] = t[(size_t)colidx[i + j] * 8 + lane];
#pragma unroll
    for (int j = 0; j < 8; ++j) {
      f32x2 p0 = __builtin_amdgcn_cvt_pk_f32_fp8((int)v[j].x, false);
      f32x2 p1 = __builtin_amdgcn_cvt_pk_f32_fp8((int)v[j].x, true);
      f32x2 p2 = __builtin_amdgcn_cvt_pk_f32_fp8((int)v[j].y, false);
      f32x2 p3 = __builtin_amdgcn_cvt_pk_f32_fp8((int)v[j].y, true);
      s[0] += p0[0]; s[1] += p0[1]; s[2] += p1[0]; s[3] += p1[1];
      s[4] += p2[0]; s[5] += p2[1]; s[6] += p3[0]; s[7] += p3[1];
    }
  }
  for (; i < e; ++i) {
    uint2 v = t[(size_t)colidx[i] * 8 + lane];
    f32x2 p0 = __builtin_amdgcn_cvt_pk_f32_fp8((int)v.x, false);
    f32x2 p1 = __builtin_amdgcn_cvt_pk_f32_fp8((int)v.x, true);
    f32x2 p2 = __builtin_amdgcn_cvt_pk_f32_fp8((int)v.y, false);
    f32x2 p3 = __builtin_amdgcn_cvt_pk_f32_fp8((int)v.y, true);
    s[0] += p0[0]; s[1] += p0[1]; s[2] += p1[0]; s[3] += p1[1];
    s[4] += p2[0]; s[5] += p2[1]; s[6] += p3[0]; s[7] += p3[1];
  }
  float dv = deg_inv[node];
  const float* rp = &r[(size_t)node * 64 + lane * 8];
  float4 r0 = *(const float4*)&rp[0];
  float4 r1 = *(const float4*)&rp[4];
  float a[8];
  a[0] = s[0] * dv + r0.x; a[1] = s[1] * dv + r0.y;
  a[2] = s[2] * dv + r0.z; a[3] = s[3] * dv + r0.w;
  a[4] = s[4] * dv + r1.x; a[5] = s[5] * dv + r1.y;
  a[6] = s[6] * dv + r1.z; a[7] = s[7] * dv + r1.w;
  s16x8 hv;
#pragma unroll
  for (int k = 0; k < 8; ++k) {
    float ak = a[k] > 0.f ? a[k] : (expf(a[k]) - 1.f);
    hv[k] = (short)f2bf(ak);
  }
  *(s16x8*)&Xout[(size_t)node * 64 + lane * 8] = hv;
}

// ------ final gather: out = deg_inv * sum t2[src] + r[dst], t2 bf16 -------

__global__ __launch_bounds__(256) void gather_out(const uint2* __restrict__ t,
                                                  const float* __restrict__ r,
                                                  const float* __restrict__ deg_inv,
                                                  const int* __restrict__ rowstart,
                                                  const int* __restrict__ degarr,
                                                  const int* __restrict__ colidx,
                                                  float* __restrict__ out, int N) {
  constexpr int L = 8;                 // uint2 lanes per node
  int node = blockIdx.x * 32 + threadIdx.x / L;
  int lane = threadIdx.x & (L - 1);
  if (node >= N) return;
  int b = rowstart[node];
  int e = b + degarr[node];
  float s0 = 0.f, s1 = 0.f, s2 = 0.f, s3 = 0.f;
  int i = b;
  for (; i + 8 <= e; i += 8) {
    uint2 v[8];
#pragma unroll
    for (int j = 0; j < 8; ++j)
      v[j] = t[(size_t)colidx[i + j] * L + lane];
#pragma unroll
    for (int j = 0; j < 8; ++j) {
      s0 += bf2f((unsigned short)(v[j].x & 0xFFFFu));
      s1 += bf2f((unsigned short)(v[j].x >> 16));
      s2 += bf2f((unsigned short)(v[j].y & 0xFFFFu));
      s3 += bf2f((unsigned short)(v[j].y >> 16));
    }
  }
  for (; i < e; ++i) {
    uint2 v = t[(size_t)colidx[i] * L + lane];
    s0 += bf2f((unsigned short)(v.x & 0xFFFFu));
    s1 += bf2f((unsigned short)(v.x >> 16));
    s2 += bf2f((unsigned short)(v.y & 0xFFFFu));
    s3 += bf2f((unsigned short)(v.y >> 16));
  }
  float dv = deg_inv[node];
  float4 rv = *(const float4*)&r[(size_t)node * 32 + 4 * lane];
  *(float4*)&out[(size_t)node * 32 + 4 * lane] =
      make_float4(s0 * dv + rv.x, s1 * dv + rv.y, s2 * dv + rv.z, s3 * dv + rv.w);
}

// ---------------- launch ----------------

extern "C" void kernel_launch(void* const* d_in, const int* in_sizes, int n_in,
                              void* d_out, int out_size, void* d_ws, size_t ws_size,
                              hipStream_t stream) {
  const float* x   = (const float*)d_in[0];
  const int*   ei  = (const int*)d_in[1];
  const float* Wl0 = (const float*)d_in[2];
  const float* Wr0 = (const float*)d_in[3];
  const float* b0  = (const float*)d_in[4];
  const float* Wl1 = (const float*)d_in[5];
  const float* Wr1 = (const float*)d_in[6];
  const float* b1  = (const float*)d_in[7];
  const float* Wl2 = (const float*)d_in[8];
  const float* Wr2 = (const float*)d_in[9];
  const float* b2  = (const float*)d_in[10];
  float* out = (float*)d_out;

  const int N = in_sizes[0] / 64;   // 100000
  const int E = in_sizes[1] / 2;    // 1600000
  const int* srcv = ei;
  const int* dstv = ei + E;
  const int NSB = (N + SBW - 1) >> LOGSBW;   // 391

  auto al = [](size_t v) { return (v + 255) & ~(size_t)255; };
  char* w = (char*)d_ws;
  size_t oBcur = 0;
  size_t oRow  = oBcur + al(4 * (size_t)NSB);
  size_t oDeg  = oRow + al(4 * (size_t)N);
  size_t oDinv = oDeg + al(4 * (size_t)N);
  size_t oWsw  = oDinv + al(4 * (size_t)N);
  size_t oBin  = oWsw + al(2 * 20480);
  size_t oCol  = oBin + al(4 * (size_t)NSB * CAPS);
  size_t oP8   = oCol + al(4 * (size_t)NSB * CAPS);
  size_t oP16  = oP8 + al((size_t)N * 64);        // fp8 t0/t1 buffer
  size_t oX    = oP16 + al(2 * (size_t)N * 32);   // bf16 t2 buffer
  size_t oR    = oX + al(2 * (size_t)N * 64);     // bf16 h buffer
  // total = oR + 4*N*64  (~73 MiB)

  int*            bcur     = (int*)(w + oBcur);
  int*            rowstart = (int*)(w + oRow);
  int*            degarr   = (int*)(w + oDeg);
  float*          deg_inv  = (float*)(w + oDinv);
  unsigned short* Wsw      = (unsigned short*)(w + oWsw); // swizzled weights
  unsigned*       coarse   = (unsigned*)(w + oBin);
  int*            colidx   = (int*)(w + oCol);
  unsigned char*  P8       = (unsigned char*)(w + oP8);   // fp8 t0/t1
  unsigned short* P16      = (unsigned short*)(w + oP16); // bf16 t2
  unsigned short* X        = (unsigned short*)(w + oX);   // bf16 h
  float*          R        = (float*)(w + oR);            // fp32 r

  hipMemsetAsync(bcur, 0, (size_t)NSB * 4, stream);

  stage_w<<<40, 256, 0, stream>>>(Wl0, Wr0, Wl1, Wr1, Wl2, Wr2, Wsw);
  int bbl = (E + CHK - 1) / CHK;   // 782
  bin_coarse<<<bbl, 256, 0, stream>>>(srcv, dstv, bcur, coarse, NSB, E);
  super_csr<<<NSB, 256, 0, stream>>>(coarse, bcur, rowstart, degarr, deg_inv, colidx, N);

  int gb = (N + 63) / 64;          // 1563
  int ggb = (N + 31) / 32;         // 3125
  // layer 0: fp32 x -> t0 (fp8 P8), r0 (R)
  gemm0_mfma<<<gb, 256, 0, stream>>>(x, Wsw, b0, P8, R, N);
  gather_fp8<<<ggb, 256, 0, stream>>>((const uint2*)P8, R, deg_inv, rowstart,
                                      degarr, colidx, X, N);
  // layer 1: X -> t1 (fp8 P8), r1 (R)
  gemm_mfma<64, true><<<gb, 256, 0, stream>>>(X, Wsw + 8192, b1, P8, R, N);
  gather_fp8<<<ggb, 256, 0, stream>>>((const uint2*)P8, R, deg_inv, rowstart,
                                      degarr, colidx, X, N);
  // layer 2: X -> t2 (bf16 P16), r2 (R, [N][32])
  gemm_mfma<32, false><<<gb, 256, 0, stream>>>(X, Wsw + 16384, b2, P16, R, N);
  gather_out<<<ggb, 256, 0, stream>>>((const uint2*)P16, R, deg_inv, rowstart,
                                      degarr, colidx, out, N);
}